// Round 13
// baseline (133.449 us; speedup 1.0000x reference)
//
#include <hip/hip_runtime.h>

#define SEQ 200
#define HID 64
#define BT  4
#define NBLK (4096 / BT)   // 1024 blocks -> 4 per CU, 4 waves/SIMD

typedef _Float16 f16;
typedef _Float16 f16x8 __attribute__((ext_vector_type(8)));
typedef float    f32x4 __attribute__((ext_vector_type(4)));

#define LOG2E 1.44269504088896340736f

#if __has_builtin(__builtin_amdgcn_exp2f)
#define EXP2F(x) __builtin_amdgcn_exp2f(x)
#else
#define EXP2F(x) __expf(0.69314718056f * (x))
#endif
#define RCPF(x) __builtin_amdgcn_rcpf(x)

// Pre-scaled domain: i/f/o gates scaled by log2e, g gate by 2*log2e
// (folded into W_hh/W_ih/bias at load time).
__device__ __forceinline__ float sigmoid_s(float s) {
    return RCPF(1.0f + EXP2F(-s));
}
__device__ __forceinline__ float tanh_s2(float s2) {
    return fmaf(-2.0f, RCPF(1.0f + EXP2F(s2)), 1.0f);
}

// R12 structure with BT=4 + full sigma-duplication for 4 blocks/CU:
//  - fragment row R holds batch row sigma(R) = R>>2:
//    rows [0,0,0,0, 1,1,1,1, 2,2,2,2, 3,3,3,3].
//    C-row 4a+r = gates of batch a for ALL r -> lane group a reads its single
//    cell (b=a, j=jpw) from acc[q][0]. No shfl/selects; 64/64 lanes active.
//    h written to 4 duplicate fragment rows (4 ds_write_b16, off-chain).
//  - W_lin from GLOBAL, issued at step top (L2-broadcast, hidden under the
//    MFMA+trans chain) -> no 51KB wl_lds -> LDS ~7.4KB -> 4 blocks/CU.
//  - everything else as R12: setprio span, XOR-swizzled dbuf h, one
//    barrier/step, pre-scaled c_state.
__global__ __launch_bounds__(256, 4)
void qlstm_v13(const float* __restrict__ x,      // [4096, 200]
               const float* __restrict__ W_ih,   // [256]
               const float* __restrict__ W_hh,   // [256, 64]
               const float* __restrict__ b_ih,   // [256]
               const float* __restrict__ b_hh,   // [256]
               const float* __restrict__ W_lin,  // [200*64]
               const float* __restrict__ b_lin,  // [1]
               float* __restrict__ out)          // [4096]
{
    __shared__ float x_lds[BT][201];        // 3.2 KB
    __shared__ f16   h_frag[2][16 * HID];   // 4 KB dbuf, swizzled frag layout
    __shared__ float out_part[4][BT];

    const int tid = threadIdx.x;
    const int w   = tid >> 6;     // wave: j-block owner
    const int l   = tid & 63;
    const int m   = l & 15;       // B col / C col
    const int a   = l >> 4;       // k-group / C row-group = this lane's batch row
    const int b0  = blockIdx.x * BT;

    // quadrant pre-scales: i,f,o -> log2e ; g -> 2*log2e
    const float qs[4] = {LOG2E, LOG2E, 2.0f * LOG2E, LOG2E};

    // ---- stage x rows 0..3 (f32, coalesced) ----
    for (int i = tid; i < BT * SEQ; i += 256) {
        int b = i / SEQ, t = i - b * SEQ;
        x_lds[b][t] = x[(size_t)b0 * SEQ + i];
    }
    // ---- zero both h buffers (h0 = 0) ----
    for (int i = tid; i < 1024; i += 256) ((float*)h_frag)[i] = 0.0f;

    // ---- B fragments (W_hh^T, pre-scaled) once: col n=q*64+16w+m, k=kk*32+a*8+e ----
    f16x8 Bf[4][2];
    float wihq[4], biasq[4];
    #pragma unroll
    for (int q = 0; q < 4; ++q) {
        const int n = q * 64 + w * 16 + m;
        wihq[q]  = W_ih[n] * qs[q];
        biasq[q] = (b_ih[n] + b_hh[n]) * qs[q];
        #pragma unroll
        for (int kk = 0; kk < 2; ++kk) {
            const float4* p = (const float4*)(W_hh + n * HID + kk * 32 + a * 8);
            float4 lo = p[0], hi = p[1];
            f16x8 f;
            f[0] = (f16)(lo.x * qs[q]); f[1] = (f16)(lo.y * qs[q]);
            f[2] = (f16)(lo.z * qs[q]); f[3] = (f16)(lo.w * qs[q]);
            f[4] = (f16)(hi.x * qs[q]); f[5] = (f16)(hi.y * qs[q]);
            f[6] = (f16)(hi.z * qs[q]); f[7] = (f16)(hi.w * qs[q]);
            Bf[q][kk] = f;
        }
    }

    const int jpw = w * 16 + m;
    // A-frag read addrs: row m, slot s=kk*4+a, byte = m*128 + ((s^(m&7))<<4)
    const int ra0 = m * 128 + (((0 + a) ^ (m & 7)) << 4);
    const int ra1 = m * 128 + (((4 + a) ^ (m & 7)) << 4);
    // h write addrs: batch a occupies fragment rows R = 4a+r, r=0..3.
    // byte(R, j) = R*128 + (((j>>3) ^ (R&7))<<4) + (j&7)*2
    int hwr[4];
    #pragma unroll
    for (int r = 0; r < 4; ++r) {
        const int R = 4 * a + r;
        hwr[r] = R * 128 + (((jpw >> 3) ^ (R & 7)) << 4) + (jpw & 7) * 2;
    }

    const char* hbytes = (const char*)h_frag;

    float c = 0.0f, o = 0.0f;
    const float t2s = 2.0f * LOG2E;

    __syncthreads();

    for (int t = 0; t < SEQ; ++t) {
        const int rb = (t & 1) << 11;   // read-buffer byte offset
        const int wb = rb ^ 2048;       // write-buffer byte offset

        // W_lin from global, issued FIRST: consumed only by the final fma,
        // ~700cy later -> L2 latency fully hidden. L2-broadcast across blocks.
        const float wl = W_lin[t * HID + jpw];

        // ======== gate GEMM (C-in = x*W_ih + bias; all 16 C-rows = batch a) ========
        __builtin_amdgcn_s_setprio(1);
        const f16x8 A0 = *(const f16x8*)(hbytes + rb + ra0);
        const f16x8 A1 = *(const f16x8*)(hbytes + rb + ra1);
        const float xv = x_lds[a][t];

        f32x4 acc[4];
        #pragma unroll
        for (int q = 0; q < 4; ++q) {
            const float i0 = fmaf(xv, wihq[q], biasq[q]);
            f32x4 ini;
            ini[0] = i0; ini[1] = i0; ini[2] = i0; ini[3] = i0;
            f32x4 z = __builtin_amdgcn_mfma_f32_16x16x32_f16(A0, Bf[q][0], ini, 0, 0, 0);
            acc[q]  = __builtin_amdgcn_mfma_f32_16x16x32_f16(A1, Bf[q][1], z, 0, 0, 0);
        }
        __builtin_amdgcn_s_setprio(0);

        // ======== pointwise: ONE cell per lane (b=a, j=jpw) ========
        const float gi = sigmoid_s(acc[0][0]);
        const float gf = sigmoid_s(acc[1][0]);
        const float gg = tanh_s2(acc[2][0]);
        const float go = sigmoid_s(acc[3][0]);
        c = fmaf(gf, c, t2s * (gi * gg));    // c pre-scaled by 2*log2e
        const float h = go * tanh_s2(c);
        const f16 hf = (f16)h;
        *(f16*)((char*)h_frag + wb + hwr[0]) = hf;
        *(f16*)((char*)h_frag + wb + hwr[1]) = hf;
        *(f16*)((char*)h_frag + wb + hwr[2]) = hf;
        *(f16*)((char*)h_frag + wb + hwr[3]) = hf;
        o = fmaf(h, wl, o);

        __syncthreads();   // h(write-buf) complete -> next step reads it
    }

    // ---- reduce over j: 16 lanes (m) in-wave, then 4 waves via LDS ----
    float v = o;
    #pragma unroll
    for (int off = 1; off < 16; off <<= 1)
        v += __shfl_xor(v, off, 64);
    if (m == 0) out_part[w][a] = v;
    __syncthreads();
    if (tid < BT) {
        out[b0 + tid] = out_part[0][tid] + out_part[1][tid]
                      + out_part[2][tid] + out_part[3][tid] + b_lin[0];
    }
}

extern "C" void kernel_launch(void* const* d_in, const int* in_sizes, int n_in,
                              void* d_out, int out_size, void* d_ws, size_t ws_size,
                              hipStream_t stream) {
    const float* x     = (const float*)d_in[0];
    const float* W_ih  = (const float*)d_in[1];
    const float* W_hh  = (const float*)d_in[2];
    const float* b_ih  = (const float*)d_in[3];
    const float* b_hh  = (const float*)d_in[4];
    const float* W_lin = (const float*)d_in[5];
    const float* b_lin = (const float*)d_in[6];
    float* out = (float*)d_out;

    dim3 grid(NBLK);
    dim3 block(256);
    qlstm_v13<<<grid, block, 0, stream>>>(x, W_ih, W_hh, b_ih, b_hh,
                                          W_lin, b_lin, out);
}

// Round 14
// 84.507 us; speedup vs baseline: 1.5792x; 1.5792x over previous
//
#include <hip/hip_runtime.h>

#define SEQ 200
#define HID 64
#define BT  8
#define NBLK (4096 / BT)   // 512 blocks -> 2 per CU, 2 waves/SIMD

typedef _Float16 f16;
typedef _Float16 f16x8 __attribute__((ext_vector_type(8)));
typedef float    f32x4 __attribute__((ext_vector_type(4)));

#define LOG2E 1.44269504088896340736f

#if __has_builtin(__builtin_amdgcn_exp2f)
#define EXP2F(x) __builtin_amdgcn_exp2f(x)
#else
#define EXP2F(x) __expf(0.69314718056f * (x))
#endif
#define RCPF(x) __builtin_amdgcn_rcpf(x)

// R12 structure (proven, 94.8us), two audited VALU cuts:
//  1. shared-rcp: sigmoid(a)*tanh(b) = (eB-1) * rcp((1+eA)(eB+1)) -> 5 exp +
//     3 rcp per cell (was 5+5). Same hardware primitives, operands bounded.
//  2. h written only to fragment rows 4a, 4a+1 (the rows whose C outputs are
//     kept). Rows 4a+2,3 feed discarded C rows only (C[r][*] depends on
//     A[r][*] alone) and stay zero from init -> 2 ds_write instead of 4.
// Layout recap (R12): fragment row r holds batch sigma(r)=2*(r>>2)+(r&1);
// lane group a reads cells (2a, j), (2a+1, j) from acc regs 0,1 directly.
__global__ __launch_bounds__(256, 2)
void qlstm_v14(const float* __restrict__ x,      // [4096, 200]
               const float* __restrict__ W_ih,   // [256]
               const float* __restrict__ W_hh,   // [256, 64]
               const float* __restrict__ b_ih,   // [256]
               const float* __restrict__ b_hh,   // [256]
               const float* __restrict__ W_lin,  // [200*64]
               const float* __restrict__ b_lin,  // [1]
               float* __restrict__ out)          // [4096]
{
    __shared__ float x_lds[BT][201];        // 6.3 KB
    __shared__ f16   h_frag[2][16 * HID];   // 4 KB dbuf, swizzled frag layout
    __shared__ float wl_lds[SEQ * HID];     // 51.2 KB
    __shared__ float out_part[4][BT];

    const int tid = threadIdx.x;
    const int w   = tid >> 6;     // wave: j-block owner
    const int l   = tid & 63;
    const int m   = l & 15;       // B col / C col
    const int a   = l >> 4;       // k-group / C row-group
    const int b0  = blockIdx.x * BT;

    // quadrant pre-scales: i,f,o -> log2e ; g -> 2*log2e
    const float qs[4] = {LOG2E, LOG2E, 2.0f * LOG2E, LOG2E};

    // ---- stage x rows 0..7 (f32, coalesced) ----
    for (int i = tid; i < BT * SEQ; i += 256) {
        int b = i / SEQ, t = i - b * SEQ;
        x_lds[b][t] = x[(size_t)b0 * SEQ + i];
    }
    // ---- stage W_lin (float4) ----
    {
        const float4* src = (const float4*)W_lin;
        float4* dst = (float4*)wl_lds;
        for (int i = tid; i < SEQ * HID / 4; i += 256) dst[i] = src[i];
    }
    // ---- zero both h buffers (rows == 2,3 mod 4 stay zero forever) ----
    for (int i = tid; i < 1024; i += 256) ((float*)h_frag)[i] = 0.0f;

    // ---- B fragments (W_hh^T, pre-scaled) once: col n=q*64+16w+m, k=kk*32+a*8+e ----
    f16x8 Bf[4][2];
    float wihq[4], biasq[4];
    #pragma unroll
    for (int q = 0; q < 4; ++q) {
        const int n = q * 64 + w * 16 + m;
        wihq[q]  = W_ih[n] * qs[q];
        biasq[q] = (b_ih[n] + b_hh[n]) * qs[q];
        #pragma unroll
        for (int kk = 0; kk < 2; ++kk) {
            const float4* p = (const float4*)(W_hh + n * HID + kk * 32 + a * 8);
            float4 lo = p[0], hi = p[1];
            f16x8 f;
            f[0] = (f16)(lo.x * qs[q]); f[1] = (f16)(lo.y * qs[q]);
            f[2] = (f16)(lo.z * qs[q]); f[3] = (f16)(lo.w * qs[q]);
            f[4] = (f16)(hi.x * qs[q]); f[5] = (f16)(hi.y * qs[q]);
            f[6] = (f16)(hi.z * qs[q]); f[7] = (f16)(hi.w * qs[q]);
            Bf[q][kk] = f;
        }
    }

    const int jpw = w * 16 + m;
    // A-frag read addrs: row m, slot s=kk*4+a, byte = m*128 + ((s^(m&7))<<4)
    const int ra0 = m * 128 + (((0 + a) ^ (m & 7)) << 4);
    const int ra1 = m * 128 + (((4 + a) ^ (m & 7)) << 4);
    // this lane's two batch rows (direct from C regs 0,1 — no merge)
    const int bA = 2 * a;
    const int bB = 2 * a + 1;
    // h write addrs: ONLY rows 4a (batch bA) and 4a+1 (batch bB) are consumed.
    // byte(R, j) = R*128 + (((j>>3) ^ (R&7))<<4) + (j&7)*2
    const int R0 = 4 * a, R1 = 4 * a + 1;
    const int hwA = R0 * 128 + (((jpw >> 3) ^ (R0 & 7)) << 4) + (jpw & 7) * 2;
    const int hwB = R1 * 128 + (((jpw >> 3) ^ (R1 & 7)) << 4) + (jpw & 7) * 2;

    const char* hbytes = (const char*)h_frag;

    float cA = 0.0f, cB = 0.0f, oA = 0.0f, oB = 0.0f;
    const float t2s = 2.0f * LOG2E;

    __syncthreads();

    for (int t = 0; t < SEQ; ++t) {
        const int rb = (t & 1) << 11;   // read-buffer byte offset
        const int wb = rb ^ 2048;       // write-buffer byte offset

        // ======== gate GEMM (C-in = x*W_ih + bias, sigma-row mapping) ========
        __builtin_amdgcn_s_setprio(1);
        const f16x8 A0 = *(const f16x8*)(hbytes + rb + ra0);
        const f16x8 A1 = *(const f16x8*)(hbytes + rb + ra1);
        const float x0 = x_lds[bA][t];
        const float x1 = x_lds[bB][t];
        const float wl = wl_lds[t * HID + jpw];

        f32x4 acc[4];
        #pragma unroll
        for (int q = 0; q < 4; ++q) {
            const float i0 = fmaf(x0, wihq[q], biasq[q]);
            const float i1 = fmaf(x1, wihq[q], biasq[q]);
            f32x4 ini;
            ini[0] = i0; ini[1] = i1; ini[2] = i0; ini[3] = i1;
            f32x4 z = __builtin_amdgcn_mfma_f32_16x16x32_f16(A0, Bf[q][0], ini, 0, 0, 0);
            acc[q]  = __builtin_amdgcn_mfma_f32_16x16x32_f16(A1, Bf[q][1], z, 0, 0, 0);
        }
        __builtin_amdgcn_s_setprio(0);

        // ======== pointwise: two cells per thread, shared-rcp trans ========
        {
            // cell A: gates si=acc[0][0], sf=acc[1][0], sg2=acc[2][0], so=acc[3][0]
            const float eA = EXP2F(-acc[0][0]);
            const float eC = EXP2F(-acc[1][0]);
            const float eB = EXP2F(acc[2][0]);
            const float eE = EXP2F(-acc[3][0]);
            const float ig = (eB - 1.0f) * RCPF((1.0f + eA) * (eB + 1.0f));
            const float gf = RCPF(1.0f + eC);
            cA = fmaf(gf, cA, t2s * ig);          // cA pre-scaled by 2*log2e
            const float eD = EXP2F(cA);
            const float h  = (eD - 1.0f) * RCPF((1.0f + eE) * (eD + 1.0f));
            *(f16*)((char*)h_frag + wb + hwA) = (f16)h;
            oA = fmaf(h, wl, oA);
        }
        {
            const float eA = EXP2F(-acc[0][1]);
            const float eC = EXP2F(-acc[1][1]);
            const float eB = EXP2F(acc[2][1]);
            const float eE = EXP2F(-acc[3][1]);
            const float ig = (eB - 1.0f) * RCPF((1.0f + eA) * (eB + 1.0f));
            const float gf = RCPF(1.0f + eC);
            cB = fmaf(gf, cB, t2s * ig);
            const float eD = EXP2F(cB);
            const float h  = (eD - 1.0f) * RCPF((1.0f + eE) * (eD + 1.0f));
            *(f16*)((char*)h_frag + wb + hwB) = (f16)h;
            oB = fmaf(h, wl, oB);
        }

        __syncthreads();   // h(write-buf) complete -> next step reads it
    }

    // ---- reduce over j: 16 lanes (m) in-wave, then 4 waves via LDS ----
    float vA = oA, vB = oB;
    #pragma unroll
    for (int off = 1; off < 16; off <<= 1) {
        vA += __shfl_xor(vA, off, 64);
        vB += __shfl_xor(vB, off, 64);
    }
    if (m == 0) {
        out_part[w][bA] = vA;
        out_part[w][bB] = vB;
    }
    __syncthreads();
    if (tid < BT) {
        out[b0 + tid] = out_part[0][tid] + out_part[1][tid]
                      + out_part[2][tid] + out_part[3][tid] + b_lin[0];
    }
}

extern "C" void kernel_launch(void* const* d_in, const int* in_sizes, int n_in,
                              void* d_out, int out_size, void* d_ws, size_t ws_size,
                              hipStream_t stream) {
    const float* x     = (const float*)d_in[0];
    const float* W_ih  = (const float*)d_in[1];
    const float* W_hh  = (const float*)d_in[2];
    const float* b_ih  = (const float*)d_in[3];
    const float* b_hh  = (const float*)d_in[4];
    const float* W_lin = (const float*)d_in[5];
    const float* b_lin = (const float*)d_in[6];
    float* out = (float*)d_out;

    dim3 grid(NBLK);
    dim3 block(256);
    qlstm_v14<<<grid, block, 0, stream>>>(x, W_ih, W_hh, b_ih, b_hh,
                                          W_lin, b_lin, out);
}